// Round 1
// 882.145 us; speedup vs baseline: 1.0259x; 1.0259x over previous
//
#include <hip/hip_runtime.h>
#include <math.h>

#define HH 4096
#define WW 4096
#define NB 64
#define U 8
#define NGR (WW / U)    // 512 groups
#define GATE 36         // consumer starts once producer published column GATE
#define HYST 16         // extra columns of lead rebuilt after a halo stall

// halo slots: halo[(blk*WW + col)*2 + s]; s=0 -> producer row 62 (consumer r-2),
// s=1 -> row 63 (r-1). Value after column col-1 (col=0 holds initial x).
// Entry: low32 = float bits, high32 = tag (col+1). Poison never matches tags.

__device__ __forceinline__ float f4c(const float4& v, int k) {
    return (k == 0) ? v.x : ((k == 1) ? v.y : ((k == 2) ? v.z : v.w));
}

// shift all 64 lanes down by 1 at VALU speed; lane 0 receives fill's lane-0 value.
__device__ __forceinline__ float wave_shr1(float src, float fill) {
    return __int_as_float(__builtin_amdgcn_update_dpp(
        __float_as_int(fill), __float_as_int(src), 0x138, 0xF, 0xF, false));
}

// HW sin: v_sin_f32 computes sin(2*pi*x). |z| <= 3 here -> |rev| < 0.48,
// no range reduction needed. ~1-2 ulp; recurrence is contractive so the
// error does not accumulate (absmax was 0.0 even with a 2-ulp polynomial).
__device__ __forceinline__ float fast_sin(float z) {
    return __builtin_amdgcn_sinf(z * 0.15915494309189535f);  // 1/(2*pi)
}

#define COLSTEP(COL, M, K)                                                   \
    do {                                                                     \
        float am1 = wave_shr1(a, Hhi[M][K]);                                 \
        float am2 = wave_shr1(am1, Hlo[M][K]);                               \
        const float z = fmaf(am2, f4c(W2v[M][(K) >> 2], (K) & 3),            \
                        fmaf(am1, f4c(W1v[M][(K) >> 2], (K) & 3),            \
                        fmaf(a,   f4c(Wv[M][(K) >> 2],  (K) & 3),            \
                                  f4c(Bv[M][(K) >> 2],  (K) & 3))));         \
        a = fast_sin(z);                                                     \
        if (lane >= 62 && (COL) + 1 < WW) {                                  \
            unsigned long long v =                                           \
                ((unsigned long long)(unsigned)((COL) + 2) << 32) |          \
                (unsigned long long)__float_as_uint(a);                      \
            atomicExch(&hme[(size_t)((COL) + 1) * 2 + (lane - 62)], v);      \
        }                                                                    \
    } while (0)

#define LOADW(M, J)                                                          \
    do {                                                                     \
        const int _j = (J);                                                  \
        Wv[M][0]  = *(const float4*)(wp  + _j);                              \
        Wv[M][1]  = *(const float4*)(wp  + _j + 4);                          \
        W1v[M][0] = *(const float4*)(wp1 + _j);                              \
        W1v[M][1] = *(const float4*)(wp1 + _j + 4);                          \
        W2v[M][0] = *(const float4*)(wp2 + _j);                              \
        W2v[M][1] = *(const float4*)(wp2 + _j + 4);                          \
        Bv[M][0]  = *(const float4*)(bp  + _j);                              \
        Bv[M][1]  = *(const float4*)(bp  + _j + 4);                          \
    } while (0)

// tag-check + broadcast-unpack group GIDX's halo (raw in Hg[SLOT]) into
// Hlo[BUF]/Hhi[BUF]. Off the serial chain, one group ahead of use; raw data
// fetched 4 groups (32 columns) ahead.
//
// Stall path (rare): on tag mismatch, rebuild HYST columns of extra producer
// lead via a sentinel poll (lane 0, fine sleep) BEFORE refetching. Resuming at
// minimum lead locks the convoy at the poll quantum every group; hysteresis
// makes stalls rare random-walk events instead.
#define UNPACKG(GIDX, BUF, SLOT)                                             \
    do {                                                                     \
        const int _jn = (GIDX) * U;                                          \
        if (blk > 0) {                                                       \
            bool myok = (lane >= 16) ||                                      \
                ((unsigned)(Hg[SLOT] >> 32) ==                               \
                 (unsigned)(_jn + (lane >> 1) + 1));                         \
            if (__builtin_expect(!__all(myok), 0)) {                         \
                const int _js = (_jn + U + HYST < WW) ? (_jn + U + HYST)     \
                                                      : (WW - 1);            \
                if (lane == 0) {                                             \
                    while ((unsigned)(atomicOr(&hsrc[(size_t)_js * 2], 0ULL) \
                                      >> 32) != (unsigned)(_js + 1)) {       \
                        __builtin_amdgcn_s_sleep(2);                         \
                    }                                                        \
                }                                                            \
                for (;;) {                                                   \
                    if (lane < 16)                                           \
                        Hg[SLOT] = atomicOr(&hsrc[(size_t)_jn * 2 + lane],   \
                                            0ULL);                           \
                    myok = (lane >= 16) ||                                   \
                        ((unsigned)(Hg[SLOT] >> 32) ==                       \
                         (unsigned)(_jn + (lane >> 1) + 1));                 \
                    if (__all(myok)) break;                                  \
                    __builtin_amdgcn_s_sleep(4);                             \
                }                                                            \
            }                                                                \
            float _hv = __uint_as_float((unsigned)(Hg[SLOT] & 0xffffffffu)); \
            _Pragma("unroll")                                                \
            for (int k = 0; k < U; ++k) {                                    \
                Hlo[BUF][k] = __shfl(_hv, 2 * k);                            \
                Hhi[BUF][k] = __shfl(_hv, 2 * k + 1);                        \
            }                                                                \
        }                                                                    \
    } while (0)

#define GROUPBODY(S)                                                         \
    do {                                                                     \
        const int G  = g4 * 4 + (S);                                         \
        const int jb = G * U;                                                \
        if (G + 1 < NGR) UNPACKG(G + 1, ((S) + 1) & 1, ((S) + 1) & 3);       \
        _Pragma("unroll")                                                    \
        for (int k = 0; k < U; ++k) COLSTEP(jb + k, (S) & 1, k);             \
        const int jw = jb + 2 * U;                                           \
        if (jw < WW) LOADW((S) & 1, jw);                                     \
        const int jh = jb + 4 * U;                                           \
        if (jh < WW && blk > 0 && lane < 16)                                 \
            Hg[S] = atomicOr(&hsrc[(size_t)jh * 2 + lane], 0ULL);            \
    } while (0)

__global__ __launch_bounds__(64, 1) void neural_grid_scan(
    const float* __restrict__ x, const float* __restrict__ w,
    const float* __restrict__ bb, float* __restrict__ out,
    unsigned long long* __restrict__ halo)
{
    const int lane = threadIdx.x;
    const int blk  = blockIdx.x;
    const int row  = blk * 64 + lane;
    const int r1 = (row >= 1) ? row - 1 : 0;   // am1==0 there, value unused
    const int r2 = (row >= 2) ? row - 2 : 0;

    const float* wp  = w  + (size_t)row * WW;
    const float* wp1 = w  + (size_t)r1  * WW;
    const float* wp2 = w  + (size_t)r2  * WW;
    const float* bp  = bb + (size_t)row * WW;

    unsigned long long* hme  = halo + (size_t)blk * WW * 2;
    unsigned long long* hsrc = halo + (size_t)(blk - 1) * WW * 2;

    float a = x[row];

    // publish initial state (column -1 == x) into slot 0, tag 1 (before gating)
    if (lane >= 62) {
        unsigned long long v = (1ULL << 32) | (unsigned long long)__float_as_uint(a);
        atomicExch(&hme[lane - 62], v);
    }

    // ---- start gate: producer must be GATE columns ahead; keeps the 32-col
    // halo prefetch fresh at start -> no atomic RT on the serial chain.
    if (blk > 0 && lane == 0) {
        while ((unsigned)(atomicOr(&hsrc[(size_t)GATE * 2], 0ULL) >> 32)
               != (unsigned)(GATE + 1)) {
            __builtin_amdgcn_s_sleep(8);
        }
    }

    float4 Wv[2][2], W1v[2][2], W2v[2][2], Bv[2][2];
    unsigned long long Hg[4];
    float Hlo[2][U] = {}, Hhi[2][U] = {};

    LOADW(0, 0);
    LOADW(1, U);
    if (blk > 0 && lane < 16) {
        Hg[0] = atomicOr(&hsrc[(size_t)(0 * U) * 2 + lane], 0ULL);
        Hg[1] = atomicOr(&hsrc[(size_t)(1 * U) * 2 + lane], 0ULL);
        Hg[2] = atomicOr(&hsrc[(size_t)(2 * U) * 2 + lane], 0ULL);
        Hg[3] = atomicOr(&hsrc[(size_t)(3 * U) * 2 + lane], 0ULL);
    } else {
        Hg[0] = Hg[1] = Hg[2] = Hg[3] = 0;
    }
    UNPACKG(0, 0, 0);   // group 0 -> buf 0

    for (int g4 = 0; g4 < NGR / 4; ++g4) {
        GROUPBODY(0);
        GROUPBODY(1);
        GROUPBODY(2);
        GROUPBODY(3);
    }

    out[row] = a;
}

extern "C" void kernel_launch(void* const* d_in, const int* in_sizes, int n_in,
                              void* d_out, int out_size, void* d_ws, size_t ws_size,
                              hipStream_t stream) {
    const float* x = (const float*)d_in[0];
    const float* w = (const float*)d_in[1];
    const float* b = (const float*)d_in[2];
    float* out = (float*)d_out;
    unsigned long long* halo = (unsigned long long*)d_ws;
    neural_grid_scan<<<dim3(NB), dim3(64), 0, stream>>>(x, w, b, out, halo);
}